// Round 12
// baseline (1856.484 us; speedup 1.0000x reference)
//
#include <hip/hip_runtime.h>

#define U_N 150000
#define I_N 100000
#define D_N 64
#define E_N 1500000
#define N_NODES (U_N + I_N)

// bucket geometry
#define BSHIFT 10
#define BW (1 << BSHIFT)              // 1024 keys per bucket
#define NB_U ((U_N + BW - 1) / BW)    // 147
#define NB_I ((I_N + BW - 1) / BW)    // 98
#define NBMAX 256
#define CAP_U 16384
#define CAP_I 24576
#define CH2 4096

typedef unsigned int uint;
typedef unsigned short ushort_t;

// bf16 helpers
__device__ __forceinline__ float bf_lo(uint x) { return __uint_as_float(x << 16); }
__device__ __forceinline__ float bf_hi(uint x) { return __uint_as_float(x & 0xFFFF0000u); }
__device__ __forceinline__ ushort_t f2b(float f) {
    uint u = __float_as_uint(f);
    uint r = u + 0x7FFFu + ((u >> 16) & 1u);   // round-to-nearest-even
    return (ushort_t)(r >> 16);
}
__device__ __forceinline__ void acc4(float4& acc, float wgt, uint2 q) {
    acc.x = fmaf(wgt, bf_lo(q.x), acc.x);
    acc.y = fmaf(wgt, bf_hi(q.x), acc.y);
    acc.z = fmaf(wgt, bf_lo(q.y), acc.z);
    acc.w = fmaf(wgt, bf_hi(q.y), acc.w);
}

// ============================================================
// stage both directions in ONE pass over the edge list.
// staged word = (payload << 10) | (key & 1023)
// ============================================================
__global__ __launch_bounds__(256) void stage_both_kernel(
    const int* __restrict__ eu, const int* __restrict__ ei,
    int* __restrict__ bcnt, uint* __restrict__ stg_u, uint* __restrict__ stg_i) {
    __shared__ uint spu[CH2], spi[CH2];
    __shared__ unsigned char sbu[CH2], sbi[CH2];
    __shared__ int histu[NBMAX], scanu[NBMAX], curu[NBMAX], gbu[NBMAX];
    __shared__ int histi[NBMAX], scani[NBMAX], curi[NBMAX], gbi[NBMAX];
    int tid = threadIdx.x;
    int e0 = blockIdx.x * CH2;
    int cnt = E_N - e0;
    if (cnt <= 0) return;
    if (cnt > CH2) cnt = CH2;

    histu[tid] = 0; histi[tid] = 0;
    __syncthreads();
    for (int s = tid; s < cnt; s += 256) {
        atomicAdd(&histu[eu[e0 + s] >> BSHIFT], 1);
        atomicAdd(&histi[ei[e0 + s] >> BSHIFT], 1);
    }
    __syncthreads();
    scanu[tid] = histu[tid]; scani[tid] = histi[tid];
    __syncthreads();
    for (int off = 1; off < NBMAX; off <<= 1) {
        int vu = (tid >= off) ? scanu[tid - off] : 0;
        int vi = (tid >= off) ? scani[tid - off] : 0;
        __syncthreads();
        scanu[tid] += vu; scani[tid] += vi;
        __syncthreads();
    }
    curu[tid] = scanu[tid] - histu[tid];
    curi[tid] = scani[tid] - histi[tid];
    __syncthreads();
    for (int s = tid; s < cnt; s += 256) {
        int ku = eu[e0 + s], ki = ei[e0 + s];
        int bu = ku >> BSHIFT, bi = ki >> BSHIFT;
        int pu = atomicAdd(&curu[bu], 1);
        spu[pu] = ((uint)ki << BSHIFT) | (uint)(ku & (BW - 1));
        sbu[pu] = (unsigned char)bu;
        int pi = atomicAdd(&curi[bi], 1);
        spi[pi] = ((uint)ku << BSHIFT) | (uint)(ki & (BW - 1));
        sbi[pi] = (unsigned char)bi;
    }
    __syncthreads();
    {
        int cu = histu[tid];
        gbu[tid] = cu ? atomicAdd(&bcnt[tid], cu) : 0;
        int ci = histi[tid];
        gbi[tid] = ci ? atomicAdd(&bcnt[NB_U + tid], ci) : 0;
    }
    __syncthreads();
    for (int s = tid; s < cnt; s += 256) {
        int b = sbu[s];
        int dst = gbu[b] + (s - (scanu[b] - histu[b]));
        if (dst < CAP_U) stg_u[(size_t)b * CAP_U + dst] = spu[s];
    }
    for (int s = tid; s < cnt; s += 256) {
        int b = sbi[s];
        int dst = gbi[b] + (s - (scani[b] - histi[b]));
        if (dst < CAP_I) stg_i[(size_t)b * CAP_I + dst] = spi[s];
    }
}

// ============================================================
// scan bucket totals -> bucket bases; seal rowptr ends
// ============================================================
__global__ void bscan_kernel(const int* __restrict__ bcnt, int* __restrict__ bbase,
                             int* __restrict__ rp_u, int* __restrict__ rp_i) {
    __shared__ int lds[NBMAX];
    int tid = threadIdx.x;
    int v = (tid < NB_U) ? bcnt[tid] : 0;
    lds[tid] = v;
    __syncthreads();
    for (int off = 1; off < NBMAX; off <<= 1) {
        int t = (tid >= off) ? lds[tid - off] : 0;
        __syncthreads();
        lds[tid] += t;
        __syncthreads();
    }
    if (tid < NB_U) bbase[tid] = lds[tid] - v;
    __syncthreads();
    int w = (tid < NB_I) ? bcnt[NB_U + tid] : 0;
    lds[tid] = w;
    __syncthreads();
    for (int off = 1; off < NBMAX; off <<= 1) {
        int t = (tid >= off) ? lds[tid - off] : 0;
        __syncthreads();
        lds[tid] += t;
        __syncthreads();
    }
    if (tid < NB_I) bbase[NB_U + tid] = lds[tid] - w;
    if (tid == 0) { rp_u[U_N] = E_N; rp_i[I_N] = E_N; }
}

// ============================================================
// csr_finish: per-bucket histogram -> dinv + rowptr, then scatter
// ============================================================
__global__ __launch_bounds__(256) void csr_finish_kernel(
    const uint* __restrict__ stg_u, const uint* __restrict__ stg_i,
    const int* __restrict__ bcnt, const int* __restrict__ bbase,
    float* __restrict__ dinv, int* __restrict__ rp_u, int* __restrict__ rp_i,
    int* __restrict__ colw_u, int* __restrict__ colw_i) {
    __shared__ int cnt[BW];
    __shared__ int cur[BW];
    __shared__ int part[256];
    int b = blockIdx.x;
    const uint* stg; int cap, lo, nkeys; float* dside; int* rowptr; int* colw;
    if (b < NB_U) {
        stg = stg_u + (size_t)b * CAP_U; cap = CAP_U; lo = b << BSHIFT;
        nkeys = U_N; dside = dinv; rowptr = rp_u; colw = colw_u;
    } else {
        int bb = b - NB_U;
        stg = stg_i + (size_t)bb * CAP_I; cap = CAP_I; lo = bb << BSHIFT;
        nkeys = I_N; dside = dinv + U_N; rowptr = rp_i; colw = colw_i;
    }
    int ns = bcnt[b]; if (ns > cap) ns = cap;
    int base = bbase[b];
    int hi = lo + BW; if (hi > nkeys) hi = nkeys;
    int nk = hi - lo;
    int tid = threadIdx.x;
    for (int k = tid; k < BW; k += 256) cnt[k] = 0;
    __syncthreads();
    for (int s = tid; s < ns; s += 256)
        atomicAdd(&cnt[stg[s] & (BW - 1)], 1);
    __syncthreads();
    for (int k = tid; k < nk; k += 256)
        dside[lo + k] = rsqrtf((float)cnt[k] + 1e-7f);
    int b4 = tid * 4;
    int v0 = cnt[b4], v1 = cnt[b4 + 1], v2 = cnt[b4 + 2], v3 = cnt[b4 + 3];
    int s = v0 + v1 + v2 + v3;
    part[tid] = s;
    __syncthreads();
    for (int off = 1; off < 256; off <<= 1) {
        int t = (tid >= off) ? part[tid - off] : 0;
        __syncthreads();
        part[tid] += t;
        __syncthreads();
    }
    int run = base + part[tid] - s;
    cur[b4] = run;
    if (b4 < nk) rowptr[lo + b4] = run;
    run += v0;
    cur[b4 + 1] = run;
    if (b4 + 1 < nk) rowptr[lo + b4 + 1] = run;
    run += v1;
    cur[b4 + 2] = run;
    if (b4 + 2 < nk) rowptr[lo + b4 + 2] = run;
    run += v2;
    cur[b4 + 3] = run;
    if (b4 + 3 < nk) rowptr[lo + b4 + 3] = run;
    __syncthreads();
    for (int s2 = tid; s2 < ns; s2 += 256) {
        uint pr = stg[s2];
        int pos = atomicAdd(&cur[pr & (BW - 1)], 1);
        colw[pos] = (int)(pr >> BSHIFT);
    }
}

// ============================================================
// degree-sorted permutation (counting sort over deg in [0,256))
// ============================================================
__device__ __forceinline__ int node_deg(const int* rp_u, const int* rp_i, int t) {
    int deg;
    if (t < U_N) deg = rp_u[t + 1] - rp_u[t];
    else { int i = t - U_N; deg = rp_i[i + 1] - rp_i[i]; }
    return (deg > 255) ? 255 : deg;
}

__global__ void deg_hist_kernel(const int* __restrict__ rp_u, const int* __restrict__ rp_i,
                                int* __restrict__ dhist) {
    int t = blockIdx.x * blockDim.x + threadIdx.x;
    if (t >= N_NODES) return;
    atomicAdd(&dhist[node_deg(rp_u, rp_i, t)], 1);
}

__global__ void deg_scan_kernel(int* __restrict__ dhist) {
    __shared__ int lds[256];
    int tid = threadIdx.x;
    int v = dhist[tid];
    lds[tid] = v;
    __syncthreads();
    for (int off = 1; off < 256; off <<= 1) {
        int t = (tid >= off) ? lds[tid - off] : 0;
        __syncthreads();
        lds[tid] += t;
        __syncthreads();
    }
    dhist[tid] = lds[tid] - v;   // exclusive base -> reused as cursor
}

__global__ void perm_fill_kernel(const int* __restrict__ rp_u, const int* __restrict__ rp_i,
                                 int* __restrict__ dcur, int* __restrict__ perm) {
    int t = blockIdx.x * blockDim.x + threadIdx.x;
    if (t >= N_NODES) return;
    int pos = atomicAdd(&dcur[node_deg(rp_u, rp_i, t)], 1);
    perm[pos] = t;
}

// ============================================================
// cvt: ego (fp32 u_emb|v_emb) -> bf16 [N][64]
// ============================================================
__global__ void cvt16_kernel(const float* __restrict__ u_emb, const float* __restrict__ v_emb,
                             ushort_t* __restrict__ dst) {
    size_t t = (size_t)blockIdx.x * blockDim.x + threadIdx.x;
    size_t stride = (size_t)gridDim.x * blockDim.x;
    const size_t nu4 = (size_t)U_N * 16;
    const size_t n4 = (size_t)N_NODES * 16;
    const float4* us = (const float4*)u_emb;
    const float4* vs = (const float4*)v_emb;
    ushort4* o = (ushort4*)dst;
    for (size_t i = t; i < n4; i += stride) {
        float4 x = (i < nu4) ? us[i] : vs[i - nu4];
        ushort4 y;
        y.x = f2b(x.x); y.y = f2b(x.y); y.z = f2b(x.z); y.w = f2b(x.w);
        o[i] = y;
    }
}

// ============================================================
// CSR gather: one 16-lane group per node slot; node = perm[slot]
// (degree-equalized within a wave -> no divergence waste).
// ============================================================
template <int FUSE>
__global__ void gather16_kernel(const ushort_t* __restrict__ src16,
                                const int* __restrict__ rowptr_u, const int* __restrict__ colw_u,
                                const int* __restrict__ rowptr_i, const int* __restrict__ colw_i,
                                const float* __restrict__ dinv,
                                const int* __restrict__ perm,
                                ushort_t* __restrict__ h16_out,
                                const ushort_t* __restrict__ ego16,
                                const ushort_t* __restrict__ h1_16,
                                float* __restrict__ out) {
    int slot = (int)((blockIdx.x * blockDim.x + threadIdx.x) >> 4);
    int d4 = threadIdx.x & 15;
    if (slot >= N_NODES) return;
    int grp = perm[slot];
    const int* rp; const int* cw; const uint2* s8; const float* dnbr; int row;
    if (grp < U_N) {
        rp = rowptr_u; cw = colw_u; row = grp; dnbr = dinv + U_N;
        s8 = (const uint2*)(src16 + (size_t)U_N * D_N);   // items block
    } else {
        rp = rowptr_i; cw = colw_i; row = grp - U_N; dnbr = dinv;
        s8 = (const uint2*)src16;                          // users block
    }
    int beg = rp[row], end = rp[row + 1];

    float4 acc = make_float4(0.f, 0.f, 0.f, 0.f);
    int j = beg;
    while (j + 8 <= end) {
        int c[8]; float wv[8]; uint2 q[8];
#pragma unroll
        for (int t = 0; t < 8; ++t) c[t] = cw[j + t];
#pragma unroll
        for (int t = 0; t < 8; ++t) wv[t] = dnbr[c[t]];
#pragma unroll
        for (int t = 0; t < 8; ++t) q[t] = s8[(size_t)c[t] * 16 + d4];
#pragma unroll
        for (int t = 0; t < 8; ++t) acc4(acc, wv[t], q[t]);
        j += 8;
    }
    if (j + 4 <= end) {
        int c[4]; float wv[4]; uint2 q[4];
#pragma unroll
        for (int t = 0; t < 4; ++t) c[t] = cw[j + t];
#pragma unroll
        for (int t = 0; t < 4; ++t) wv[t] = dnbr[c[t]];
#pragma unroll
        for (int t = 0; t < 4; ++t) q[t] = s8[(size_t)c[t] * 16 + d4];
#pragma unroll
        for (int t = 0; t < 4; ++t) acc4(acc, wv[t], q[t]);
        j += 4;
    }
    for (; j < end; ++j) {
        int c = cw[j];
        float wgt = dnbr[c];
        uint2 q = s8[(size_t)c * 16 + d4];
        acc4(acc, wgt, q);
    }

    float sc = rsqrtf((float)(end - beg) + 1e-7f);
    acc.x *= sc; acc.y *= sc; acc.z *= sc; acc.w *= sc;

    if (FUSE == 0) {
        ushort4 o;
        o.x = f2b(acc.x); o.y = f2b(acc.y); o.z = f2b(acc.z); o.w = f2b(acc.w);
        ((ushort4*)h16_out)[(size_t)grp * 16 + d4] = o;
    } else {
        // out = 0.25*(ego + h1 + h2 + h3) (+ ego again for items); bf16 ego/h1/h2
        uint2 e  = ((const uint2*)ego16)[(size_t)grp * 16 + d4];
        uint2 p1 = ((const uint2*)h1_16)[(size_t)grp * 16 + d4];
        uint2 p2 = ((const uint2*)src16)[(size_t)grp * 16 + d4];  // src16 == h2
        float ex = bf_lo(e.x), ey = bf_hi(e.x), ez = bf_lo(e.y), ew = bf_hi(e.y);
        float4 r;
        r.x = 0.25f * (ex + bf_lo(p1.x) + bf_lo(p2.x) + acc.x);
        r.y = 0.25f * (ey + bf_hi(p1.x) + bf_hi(p2.x) + acc.y);
        r.z = 0.25f * (ez + bf_lo(p1.y) + bf_lo(p2.y) + acc.z);
        r.w = 0.25f * (ew + bf_hi(p1.y) + bf_hi(p2.y) + acc.w);
        if (grp >= U_N) { r.x += ex; r.y += ey; r.z += ez; r.w += ew; }
        ((float4*)out)[(size_t)grp * 16 + d4] = r;
    }
}

// ============================================================
// fallback (R1 atomic path) kernels, used only if ws too small
// ============================================================
__global__ void deg_kernel(const int* __restrict__ eu, const int* __restrict__ ei,
                           float* __restrict__ deg) {
    int t = blockIdx.x * blockDim.x + threadIdx.x;
    int stride = gridDim.x * blockDim.x;
    for (int e = t; e < E_N; e += stride) {
        atomicAdd(&deg[eu[e]], 1.0f);
        atomicAdd(&deg[U_N + ei[e]], 1.0f);
    }
}
__global__ void rsqrt_kernel(float* __restrict__ deg) {
    int t = blockIdx.x * blockDim.x + threadIdx.x;
    if (t < N_NODES) deg[t] = rsqrtf(deg[t] + 1e-7f);
}
__global__ void init_out_kernel(const float* __restrict__ u_emb,
                                const float* __restrict__ v_emb,
                                float* __restrict__ out) {
    size_t t = (size_t)blockIdx.x * blockDim.x + threadIdx.x;
    size_t stride = (size_t)gridDim.x * blockDim.x;
    const size_t nu4 = (size_t)U_N * D_N / 4;
    const size_t ni4 = (size_t)I_N * D_N / 4;
    const float4* us = (const float4*)u_emb;
    const float4* vs = (const float4*)v_emb;
    float4* o = (float4*)out;
    for (size_t i = t; i < nu4; i += stride) o[i] = us[i];
    for (size_t i = t; i < ni4; i += stride) o[nu4 + i] = vs[i];
}
__global__ void add_kernel(float* __restrict__ acc, const float* __restrict__ h) {
    size_t t = (size_t)blockIdx.x * blockDim.x + threadIdx.x;
    size_t stride = (size_t)gridDim.x * blockDim.x;
    const size_t n4 = (size_t)N_NODES * D_N / 4;
    float4* a = (float4*)acc;
    const float4* b = (const float4*)h;
    for (size_t i = t; i < n4; i += stride) {
        float4 x = a[i]; float4 y = b[i];
        x.x += y.x; x.y += y.y; x.z += y.z; x.w += y.w;
        a[i] = x;
    }
}
__global__ void prop_kernel(const float* __restrict__ srcU, const float* __restrict__ srcI,
                            float* __restrict__ dstU, float* __restrict__ dstI,
                            const int* __restrict__ eu, const int* __restrict__ ei,
                            const float* __restrict__ dinv) {
    int wave = (blockIdx.x * blockDim.x + threadIdx.x) >> 6;
    int lane = threadIdx.x & 63;
    int nwaves = (gridDim.x * blockDim.x) >> 6;
    for (int e = wave; e < E_N; e += nwaves) {
        int u = eu[e];
        int i = ei[e];
        float w = dinv[u] * dinv[U_N + i];
        float hu = srcU[(size_t)u * D_N + lane];
        float hi = srcI[(size_t)i * D_N + lane];
        atomicAdd(&dstU[(size_t)u * D_N + lane], w * hi);
        atomicAdd(&dstI[(size_t)i * D_N + lane], w * hu);
    }
}
__global__ void final_kernel(float* __restrict__ out, const float* __restrict__ v_emb) {
    size_t t = (size_t)blockIdx.x * blockDim.x + threadIdx.x;
    size_t stride = (size_t)gridDim.x * blockDim.x;
    const size_t nu4 = (size_t)U_N * D_N / 4;
    const size_t n4 = (size_t)N_NODES * D_N / 4;
    float4* o = (float4*)out;
    const float4* v = (const float4*)v_emb;
    for (size_t i = t; i < n4; i += stride) {
        float4 x = o[i];
        x.x *= 0.25f; x.y *= 0.25f; x.z *= 0.25f; x.w *= 0.25f;
        if (i >= nu4) {
            float4 vv = v[i - nu4];
            x.x += vv.x; x.y += vv.y; x.z += vv.z; x.w += vv.w;
        }
        o[i] = x;
    }
}

// ============================================================
extern "C" void kernel_launch(void* const* d_in, const int* in_sizes, int n_in,
                              void* d_out, int out_size, void* d_ws, size_t ws_size,
                              hipStream_t stream) {
    const float* u_emb = (const float*)d_in[0];
    const float* v_emb = (const float*)d_in[1];
    const int* eu = (const int*)d_in[2];
    const int* ei = (const int*)d_in[3];
    float* out = (float*)d_out;

    const size_t h16bytes = (size_t)N_NODES * D_N * sizeof(ushort_t);  // 32 MB

    size_t off = 0;
    auto carve = [&](size_t bytes) {
        size_t p = off;
        off = (off + bytes + 255) & ~(size_t)255;
        return p;
    };
    char* ws = (char*)d_ws;
    size_t o_dinv  = carve((size_t)N_NODES * 4);
    size_t o_rpu   = carve((size_t)(U_N + 1) * 4);
    size_t o_rpi   = carve((size_t)(I_N + 1) * 4);
    size_t o_bcnt  = carve((size_t)(NB_U + NBMAX) * 4);
    size_t o_bbase = carve((size_t)(NB_U + NBMAX) * 4);
    size_t o_dhist = carve((size_t)256 * 4);
    size_t o_perm  = carve((size_t)N_NODES * 4);
    size_t o_colu  = carve((size_t)E_N * 4);   // payload only
    size_t o_coli  = carve((size_t)E_N * 4);
    size_t o_ego16 = carve(h16bytes);
    size_t o_h1    = carve(h16bytes);          // aliased: stg_u during build (9.6 MB)
    size_t o_h2    = carve(h16bytes);          // aliased: stg_i during build (9.6 MB)
    size_t needed = off;

    if (ws_size >= needed) {
        float* dinv = (float*)(ws + o_dinv);
        int* rp_u  = (int*)(ws + o_rpu);
        int* rp_i  = (int*)(ws + o_rpi);
        int* bcnt  = (int*)(ws + o_bcnt);
        int* bbase = (int*)(ws + o_bbase);
        int* dhist = (int*)(ws + o_dhist);
        int* perm  = (int*)(ws + o_perm);
        int* colw_u = (int*)(ws + o_colu);
        int* colw_i = (int*)(ws + o_coli);
        ushort_t* ego16 = (ushort_t*)(ws + o_ego16);
        ushort_t* h1_16 = (ushort_t*)(ws + o_h1);
        ushort_t* h2_16 = (ushort_t*)(ws + o_h2);
        uint* stg_u = (uint*)(ws + o_h1);
        uint* stg_i = (uint*)(ws + o_h2);

        hipMemsetAsync(bcnt, 0, (size_t)(NB_U + NBMAX) * 4, stream);
        hipMemsetAsync(dhist, 0, (size_t)256 * 4, stream);

        cvt16_kernel<<<2048, 256, 0, stream>>>(u_emb, v_emb, ego16);

        const int sblocks = (E_N + CH2 - 1) / CH2;
        stage_both_kernel<<<sblocks, NBMAX, 0, stream>>>(eu, ei, bcnt, stg_u, stg_i);
        bscan_kernel<<<1, NBMAX, 0, stream>>>(bcnt, bbase, rp_u, rp_i);
        csr_finish_kernel<<<NB_U + NB_I, 256, 0, stream>>>(stg_u, stg_i, bcnt, bbase,
                                                           dinv, rp_u, rp_i, colw_u, colw_i);

        // degree-sorted permutation
        const int nblk = (N_NODES + 255) / 256;
        deg_hist_kernel<<<nblk, 256, 0, stream>>>(rp_u, rp_i, dhist);
        deg_scan_kernel<<<1, 256, 0, stream>>>(dhist);
        perm_fill_kernel<<<nblk, 256, 0, stream>>>(rp_u, rp_i, dhist, perm);

        const int gblocks = ((size_t)N_NODES * 16 + 255) / 256;
        // layer 1: src = ego16 -> h1 bf16
        gather16_kernel<0><<<gblocks, 256, 0, stream>>>(ego16, rp_u, colw_u, rp_i, colw_i,
                                                        dinv, perm, h1_16,
                                                        nullptr, nullptr, nullptr);
        // layer 2: src = h1 -> h2 bf16
        gather16_kernel<0><<<gblocks, 256, 0, stream>>>(h1_16, rp_u, colw_u, rp_i, colw_i,
                                                        dinv, perm, h2_16,
                                                        nullptr, nullptr, nullptr);
        // layer 3: src = h2 -> fused final epilogue (all-bf16 reads) -> out fp32
        gather16_kernel<1><<<gblocks, 256, 0, stream>>>(h2_16, rp_u, colw_u, rp_i, colw_i,
                                                        dinv, perm, nullptr,
                                                        ego16, h1_16, out);
    } else {
        // fallback: R1 atomic-scatter path
        const size_t hbytes = (size_t)N_NODES * D_N * sizeof(float);
        float* dinv = (float*)ws;
        float* bufA = (float*)(ws + (1u << 20));
        float* bufB = bufA + (size_t)N_NODES * D_N;
        hipMemsetAsync(dinv, 0, N_NODES * sizeof(float), stream);
        hipMemsetAsync(bufA, 0, hbytes, stream);
        hipMemsetAsync(bufB, 0, hbytes, stream);
        deg_kernel<<<2048, 256, 0, stream>>>(eu, ei, dinv);
        rsqrt_kernel<<<(N_NODES + 255) / 256, 256, 0, stream>>>(dinv);
        init_out_kernel<<<2048, 256, 0, stream>>>(u_emb, v_emb, out);
        float* bufA_i = bufA + (size_t)U_N * D_N;
        float* bufB_i = bufB + (size_t)U_N * D_N;
        float* out_i  = out + (size_t)U_N * D_N;
        prop_kernel<<<8192, 256, 0, stream>>>(u_emb, v_emb, bufA, bufA_i, eu, ei, dinv);
        add_kernel<<<2048, 256, 0, stream>>>(out, bufA);
        prop_kernel<<<8192, 256, 0, stream>>>(bufA, bufA_i, bufB, bufB_i, eu, ei, dinv);
        add_kernel<<<2048, 256, 0, stream>>>(out, bufB);
        prop_kernel<<<8192, 256, 0, stream>>>(bufB, bufB_i, out, out_i, eu, ei, dinv);
        final_kernel<<<2048, 256, 0, stream>>>(out, v_emb);
    }
}

// Round 13
// 337.866 us; speedup vs baseline: 5.4947x; 5.4947x over previous
//
#include <hip/hip_runtime.h>

#define U_N 150000
#define I_N 100000
#define D_N 64
#define E_N 1500000
#define N_NODES (U_N + I_N)

// bucket geometry
#define BSHIFT 10
#define BW (1 << BSHIFT)              // 1024 keys per bucket
#define NB_U ((U_N + BW - 1) / BW)    // 147
#define NB_I ((I_N + BW - 1) / BW)    // 98
#define NBMAX 256
#define CAP_U 16384
#define CAP_I 24576
#define CH2 4096

// degree-sort geometry
#define NPB_SORT 64
#define SORT_CHUNK ((N_NODES + NPB_SORT - 1) / NPB_SORT)   // 3907

typedef unsigned int uint;
typedef unsigned short ushort_t;

// bf16 helpers
__device__ __forceinline__ float bf_lo(uint x) { return __uint_as_float(x << 16); }
__device__ __forceinline__ float bf_hi(uint x) { return __uint_as_float(x & 0xFFFF0000u); }
__device__ __forceinline__ ushort_t f2b(float f) {
    uint u = __float_as_uint(f);
    uint r = u + 0x7FFFu + ((u >> 16) & 1u);   // round-to-nearest-even
    return (ushort_t)(r >> 16);
}
__device__ __forceinline__ void acc4(float4& acc, float wgt, uint2 q) {
    acc.x = fmaf(wgt, bf_lo(q.x), acc.x);
    acc.y = fmaf(wgt, bf_hi(q.x), acc.y);
    acc.z = fmaf(wgt, bf_lo(q.y), acc.z);
    acc.w = fmaf(wgt, bf_hi(q.y), acc.w);
}

// ============================================================
// stage both directions in ONE pass over the edge list.
// staged word = (payload << 10) | (key & 1023)
// ============================================================
__global__ __launch_bounds__(256) void stage_both_kernel(
    const int* __restrict__ eu, const int* __restrict__ ei,
    int* __restrict__ bcnt, uint* __restrict__ stg_u, uint* __restrict__ stg_i) {
    __shared__ uint spu[CH2], spi[CH2];
    __shared__ unsigned char sbu[CH2], sbi[CH2];
    __shared__ int histu[NBMAX], scanu[NBMAX], curu[NBMAX], gbu[NBMAX];
    __shared__ int histi[NBMAX], scani[NBMAX], curi[NBMAX], gbi[NBMAX];
    int tid = threadIdx.x;
    int e0 = blockIdx.x * CH2;
    int cnt = E_N - e0;
    if (cnt <= 0) return;
    if (cnt > CH2) cnt = CH2;

    histu[tid] = 0; histi[tid] = 0;
    __syncthreads();
    for (int s = tid; s < cnt; s += 256) {
        atomicAdd(&histu[eu[e0 + s] >> BSHIFT], 1);
        atomicAdd(&histi[ei[e0 + s] >> BSHIFT], 1);
    }
    __syncthreads();
    scanu[tid] = histu[tid]; scani[tid] = histi[tid];
    __syncthreads();
    for (int off = 1; off < NBMAX; off <<= 1) {
        int vu = (tid >= off) ? scanu[tid - off] : 0;
        int vi = (tid >= off) ? scani[tid - off] : 0;
        __syncthreads();
        scanu[tid] += vu; scani[tid] += vi;
        __syncthreads();
    }
    curu[tid] = scanu[tid] - histu[tid];
    curi[tid] = scani[tid] - histi[tid];
    __syncthreads();
    for (int s = tid; s < cnt; s += 256) {
        int ku = eu[e0 + s], ki = ei[e0 + s];
        int bu = ku >> BSHIFT, bi = ki >> BSHIFT;
        int pu = atomicAdd(&curu[bu], 1);
        spu[pu] = ((uint)ki << BSHIFT) | (uint)(ku & (BW - 1));
        sbu[pu] = (unsigned char)bu;
        int pi = atomicAdd(&curi[bi], 1);
        spi[pi] = ((uint)ku << BSHIFT) | (uint)(ki & (BW - 1));
        sbi[pi] = (unsigned char)bi;
    }
    __syncthreads();
    {
        int cu = histu[tid];
        gbu[tid] = cu ? atomicAdd(&bcnt[tid], cu) : 0;
        int ci = histi[tid];
        gbi[tid] = ci ? atomicAdd(&bcnt[NB_U + tid], ci) : 0;
    }
    __syncthreads();
    for (int s = tid; s < cnt; s += 256) {
        int b = sbu[s];
        int dst = gbu[b] + (s - (scanu[b] - histu[b]));
        if (dst < CAP_U) stg_u[(size_t)b * CAP_U + dst] = spu[s];
    }
    for (int s = tid; s < cnt; s += 256) {
        int b = sbi[s];
        int dst = gbi[b] + (s - (scani[b] - histi[b]));
        if (dst < CAP_I) stg_i[(size_t)b * CAP_I + dst] = spi[s];
    }
}

// ============================================================
// scan bucket totals -> bucket bases; seal rowptr ends
// ============================================================
__global__ void bscan_kernel(const int* __restrict__ bcnt, int* __restrict__ bbase,
                             int* __restrict__ rp_u, int* __restrict__ rp_i) {
    __shared__ int lds[NBMAX];
    int tid = threadIdx.x;
    int v = (tid < NB_U) ? bcnt[tid] : 0;
    lds[tid] = v;
    __syncthreads();
    for (int off = 1; off < NBMAX; off <<= 1) {
        int t = (tid >= off) ? lds[tid - off] : 0;
        __syncthreads();
        lds[tid] += t;
        __syncthreads();
    }
    if (tid < NB_U) bbase[tid] = lds[tid] - v;
    __syncthreads();
    int w = (tid < NB_I) ? bcnt[NB_U + tid] : 0;
    lds[tid] = w;
    __syncthreads();
    for (int off = 1; off < NBMAX; off <<= 1) {
        int t = (tid >= off) ? lds[tid - off] : 0;
        __syncthreads();
        lds[tid] += t;
        __syncthreads();
    }
    if (tid < NB_I) bbase[NB_U + tid] = lds[tid] - w;
    if (tid == 0) { rp_u[U_N] = E_N; rp_i[I_N] = E_N; }
}

// ============================================================
// csr_finish: per-bucket histogram -> dinv + rowptr, then scatter
// ============================================================
__global__ __launch_bounds__(256) void csr_finish_kernel(
    const uint* __restrict__ stg_u, const uint* __restrict__ stg_i,
    const int* __restrict__ bcnt, const int* __restrict__ bbase,
    float* __restrict__ dinv, int* __restrict__ rp_u, int* __restrict__ rp_i,
    int* __restrict__ colw_u, int* __restrict__ colw_i) {
    __shared__ int cnt[BW];
    __shared__ int cur[BW];
    __shared__ int part[256];
    int b = blockIdx.x;
    const uint* stg; int cap, lo, nkeys; float* dside; int* rowptr; int* colw;
    if (b < NB_U) {
        stg = stg_u + (size_t)b * CAP_U; cap = CAP_U; lo = b << BSHIFT;
        nkeys = U_N; dside = dinv; rowptr = rp_u; colw = colw_u;
    } else {
        int bb = b - NB_U;
        stg = stg_i + (size_t)bb * CAP_I; cap = CAP_I; lo = bb << BSHIFT;
        nkeys = I_N; dside = dinv + U_N; rowptr = rp_i; colw = colw_i;
    }
    int ns = bcnt[b]; if (ns > cap) ns = cap;
    int base = bbase[b];
    int hi = lo + BW; if (hi > nkeys) hi = nkeys;
    int nk = hi - lo;
    int tid = threadIdx.x;
    for (int k = tid; k < BW; k += 256) cnt[k] = 0;
    __syncthreads();
    for (int s = tid; s < ns; s += 256)
        atomicAdd(&cnt[stg[s] & (BW - 1)], 1);
    __syncthreads();
    for (int k = tid; k < nk; k += 256)
        dside[lo + k] = rsqrtf((float)cnt[k] + 1e-7f);
    int b4 = tid * 4;
    int v0 = cnt[b4], v1 = cnt[b4 + 1], v2 = cnt[b4 + 2], v3 = cnt[b4 + 3];
    int s = v0 + v1 + v2 + v3;
    part[tid] = s;
    __syncthreads();
    for (int off = 1; off < 256; off <<= 1) {
        int t = (tid >= off) ? part[tid - off] : 0;
        __syncthreads();
        part[tid] += t;
        __syncthreads();
    }
    int run = base + part[tid] - s;
    cur[b4] = run;
    if (b4 < nk) rowptr[lo + b4] = run;
    run += v0;
    cur[b4 + 1] = run;
    if (b4 + 1 < nk) rowptr[lo + b4 + 1] = run;
    run += v1;
    cur[b4 + 2] = run;
    if (b4 + 2 < nk) rowptr[lo + b4 + 2] = run;
    run += v2;
    cur[b4 + 3] = run;
    if (b4 + 3 < nk) rowptr[lo + b4 + 3] = run;
    __syncthreads();
    for (int s2 = tid; s2 < ns; s2 += 256) {
        uint pr = stg[s2];
        int pos = atomicAdd(&cur[pr & (BW - 1)], 1);
        colw[pos] = (int)(pr >> BSHIFT);
    }
}

// ============================================================
// degree-sorted permutation -- 3-phase contention-free counting sort
// ============================================================
__device__ __forceinline__ int node_deg(const int* rp_u, const int* rp_i, int t) {
    int deg;
    if (t < U_N) deg = rp_u[t + 1] - rp_u[t];
    else { int i = t - U_N; deg = rp_i[i + 1] - rp_i[i]; }
    return (deg > 255) ? 255 : deg;
}

// phase 1: per-block LDS histogram -> dmat[b][256]
__global__ __launch_bounds__(256) void deg_hist1_kernel(
    const int* __restrict__ rp_u, const int* __restrict__ rp_i, int* __restrict__ dmat) {
    __shared__ int h[256];
    int b = blockIdx.x;
    int tid = threadIdx.x;
    h[tid] = 0;
    __syncthreads();
    int start = b * SORT_CHUNK;
    int end = start + SORT_CHUNK; if (end > N_NODES) end = N_NODES;
    for (int t = start + tid; t < end; t += 256)
        atomicAdd(&h[node_deg(rp_u, rp_i, t)], 1);
    __syncthreads();
    dmat[b * 256 + tid] = h[tid];
}

// phase 2: single block; thread tid owns bin tid. Column totals -> bin bases
// -> per-(block,bin) base written back into dmat.
__global__ __launch_bounds__(256) void deg_scan2_kernel(int* __restrict__ dmat) {
    __shared__ int tot[256];
    int tid = threadIdx.x;
    int sum = 0;
    for (int b = 0; b < NPB_SORT; ++b) sum += dmat[b * 256 + tid];
    tot[tid] = sum;
    __syncthreads();
    for (int off = 1; off < 256; off <<= 1) {
        int t = (tid >= off) ? tot[tid - off] : 0;
        __syncthreads();
        tot[tid] += t;
        __syncthreads();
    }
    int run = tot[tid] - sum;   // exclusive base for bin tid
    for (int b = 0; b < NPB_SORT; ++b) {
        int c = dmat[b * 256 + tid];
        dmat[b * 256 + tid] = run;
        run += c;
    }
}

// phase 3: per-block LDS cursors (from dmat) -> perm, LDS atomics only
__global__ __launch_bounds__(256) void perm_fill3_kernel(
    const int* __restrict__ rp_u, const int* __restrict__ rp_i,
    const int* __restrict__ dmat, int* __restrict__ perm) {
    __shared__ int cur[256];
    int b = blockIdx.x;
    int tid = threadIdx.x;
    cur[tid] = dmat[b * 256 + tid];
    __syncthreads();
    int start = b * SORT_CHUNK;
    int end = start + SORT_CHUNK; if (end > N_NODES) end = N_NODES;
    for (int t = start + tid; t < end; t += 256) {
        int pos = atomicAdd(&cur[node_deg(rp_u, rp_i, t)], 1);
        perm[pos] = t;
    }
}

// ============================================================
// cvt: ego (fp32 u_emb|v_emb) -> bf16 [N][64]
// ============================================================
__global__ void cvt16_kernel(const float* __restrict__ u_emb, const float* __restrict__ v_emb,
                             ushort_t* __restrict__ dst) {
    size_t t = (size_t)blockIdx.x * blockDim.x + threadIdx.x;
    size_t stride = (size_t)gridDim.x * blockDim.x;
    const size_t nu4 = (size_t)U_N * 16;
    const size_t n4 = (size_t)N_NODES * 16;
    const float4* us = (const float4*)u_emb;
    const float4* vs = (const float4*)v_emb;
    ushort4* o = (ushort4*)dst;
    for (size_t i = t; i < n4; i += stride) {
        float4 x = (i < nu4) ? us[i] : vs[i - nu4];
        ushort4 y;
        y.x = f2b(x.x); y.y = f2b(x.y); y.z = f2b(x.z); y.w = f2b(x.w);
        o[i] = y;
    }
}

// ============================================================
// CSR gather: one 16-lane group per node slot; node = perm[slot]
// ============================================================
template <int FUSE>
__global__ void gather16_kernel(const ushort_t* __restrict__ src16,
                                const int* __restrict__ rowptr_u, const int* __restrict__ colw_u,
                                const int* __restrict__ rowptr_i, const int* __restrict__ colw_i,
                                const float* __restrict__ dinv,
                                const int* __restrict__ perm,
                                ushort_t* __restrict__ h16_out,
                                const ushort_t* __restrict__ ego16,
                                const ushort_t* __restrict__ h1_16,
                                float* __restrict__ out) {
    int slot = (int)((blockIdx.x * blockDim.x + threadIdx.x) >> 4);
    int d4 = threadIdx.x & 15;
    if (slot >= N_NODES) return;
    int grp = perm[slot];
    const int* rp; const int* cw; const uint2* s8; const float* dnbr; int row;
    if (grp < U_N) {
        rp = rowptr_u; cw = colw_u; row = grp; dnbr = dinv + U_N;
        s8 = (const uint2*)(src16 + (size_t)U_N * D_N);   // items block
    } else {
        rp = rowptr_i; cw = colw_i; row = grp - U_N; dnbr = dinv;
        s8 = (const uint2*)src16;                          // users block
    }
    int beg = rp[row], end = rp[row + 1];

    float4 acc = make_float4(0.f, 0.f, 0.f, 0.f);
    int j = beg;
    while (j + 8 <= end) {
        int c[8]; float wv[8]; uint2 q[8];
#pragma unroll
        for (int t = 0; t < 8; ++t) c[t] = cw[j + t];
#pragma unroll
        for (int t = 0; t < 8; ++t) wv[t] = dnbr[c[t]];
#pragma unroll
        for (int t = 0; t < 8; ++t) q[t] = s8[(size_t)c[t] * 16 + d4];
#pragma unroll
        for (int t = 0; t < 8; ++t) acc4(acc, wv[t], q[t]);
        j += 8;
    }
    if (j + 4 <= end) {
        int c[4]; float wv[4]; uint2 q[4];
#pragma unroll
        for (int t = 0; t < 4; ++t) c[t] = cw[j + t];
#pragma unroll
        for (int t = 0; t < 4; ++t) wv[t] = dnbr[c[t]];
#pragma unroll
        for (int t = 0; t < 4; ++t) q[t] = s8[(size_t)c[t] * 16 + d4];
#pragma unroll
        for (int t = 0; t < 4; ++t) acc4(acc, wv[t], q[t]);
        j += 4;
    }
    for (; j < end; ++j) {
        int c = cw[j];
        float wgt = dnbr[c];
        uint2 q = s8[(size_t)c * 16 + d4];
        acc4(acc, wgt, q);
    }

    float sc = rsqrtf((float)(end - beg) + 1e-7f);
    acc.x *= sc; acc.y *= sc; acc.z *= sc; acc.w *= sc;

    if (FUSE == 0) {
        ushort4 o;
        o.x = f2b(acc.x); o.y = f2b(acc.y); o.z = f2b(acc.z); o.w = f2b(acc.w);
        ((ushort4*)h16_out)[(size_t)grp * 16 + d4] = o;
    } else {
        // out = 0.25*(ego + h1 + h2 + h3) (+ ego again for items); bf16 ego/h1/h2
        uint2 e  = ((const uint2*)ego16)[(size_t)grp * 16 + d4];
        uint2 p1 = ((const uint2*)h1_16)[(size_t)grp * 16 + d4];
        uint2 p2 = ((const uint2*)src16)[(size_t)grp * 16 + d4];  // src16 == h2
        float ex = bf_lo(e.x), ey = bf_hi(e.x), ez = bf_lo(e.y), ew = bf_hi(e.y);
        float4 r;
        r.x = 0.25f * (ex + bf_lo(p1.x) + bf_lo(p2.x) + acc.x);
        r.y = 0.25f * (ey + bf_hi(p1.x) + bf_hi(p2.x) + acc.y);
        r.z = 0.25f * (ez + bf_lo(p1.y) + bf_lo(p2.y) + acc.z);
        r.w = 0.25f * (ew + bf_hi(p1.y) + bf_hi(p2.y) + acc.w);
        if (grp >= U_N) { r.x += ex; r.y += ey; r.z += ez; r.w += ew; }
        ((float4*)out)[(size_t)grp * 16 + d4] = r;
    }
}

// ============================================================
// fallback (R1 atomic path) kernels, used only if ws too small
// ============================================================
__global__ void deg_kernel(const int* __restrict__ eu, const int* __restrict__ ei,
                           float* __restrict__ deg) {
    int t = blockIdx.x * blockDim.x + threadIdx.x;
    int stride = gridDim.x * blockDim.x;
    for (int e = t; e < E_N; e += stride) {
        atomicAdd(&deg[eu[e]], 1.0f);
        atomicAdd(&deg[U_N + ei[e]], 1.0f);
    }
}
__global__ void rsqrt_kernel(float* __restrict__ deg) {
    int t = blockIdx.x * blockDim.x + threadIdx.x;
    if (t < N_NODES) deg[t] = rsqrtf(deg[t] + 1e-7f);
}
__global__ void init_out_kernel(const float* __restrict__ u_emb,
                                const float* __restrict__ v_emb,
                                float* __restrict__ out) {
    size_t t = (size_t)blockIdx.x * blockDim.x + threadIdx.x;
    size_t stride = (size_t)gridDim.x * blockDim.x;
    const size_t nu4 = (size_t)U_N * D_N / 4;
    const size_t ni4 = (size_t)I_N * D_N / 4;
    const float4* us = (const float4*)u_emb;
    const float4* vs = (const float4*)v_emb;
    float4* o = (float4*)out;
    for (size_t i = t; i < nu4; i += stride) o[i] = us[i];
    for (size_t i = t; i < ni4; i += stride) o[nu4 + i] = vs[i];
}
__global__ void add_kernel(float* __restrict__ acc, const float* __restrict__ h) {
    size_t t = (size_t)blockIdx.x * blockDim.x + threadIdx.x;
    size_t stride = (size_t)gridDim.x * blockDim.x;
    const size_t n4 = (size_t)N_NODES * D_N / 4;
    float4* a = (float4*)acc;
    const float4* b = (const float4*)h;
    for (size_t i = t; i < n4; i += stride) {
        float4 x = a[i]; float4 y = b[i];
        x.x += y.x; x.y += y.y; x.z += y.z; x.w += y.w;
        a[i] = x;
    }
}
__global__ void prop_kernel(const float* __restrict__ srcU, const float* __restrict__ srcI,
                            float* __restrict__ dstU, float* __restrict__ dstI,
                            const int* __restrict__ eu, const int* __restrict__ ei,
                            const float* __restrict__ dinv) {
    int wave = (blockIdx.x * blockDim.x + threadIdx.x) >> 6;
    int lane = threadIdx.x & 63;
    int nwaves = (gridDim.x * blockDim.x) >> 6;
    for (int e = wave; e < E_N; e += nwaves) {
        int u = eu[e];
        int i = ei[e];
        float w = dinv[u] * dinv[U_N + i];
        float hu = srcU[(size_t)u * D_N + lane];
        float hi = srcI[(size_t)i * D_N + lane];
        atomicAdd(&dstU[(size_t)u * D_N + lane], w * hi);
        atomicAdd(&dstI[(size_t)i * D_N + lane], w * hu);
    }
}
__global__ void final_kernel(float* __restrict__ out, const float* __restrict__ v_emb) {
    size_t t = (size_t)blockIdx.x * blockDim.x + threadIdx.x;
    size_t stride = (size_t)gridDim.x * blockDim.x;
    const size_t nu4 = (size_t)U_N * D_N / 4;
    const size_t n4 = (size_t)N_NODES * D_N / 4;
    float4* o = (float4*)out;
    const float4* v = (const float4*)v_emb;
    for (size_t i = t; i < n4; i += stride) {
        float4 x = o[i];
        x.x *= 0.25f; x.y *= 0.25f; x.z *= 0.25f; x.w *= 0.25f;
        if (i >= nu4) {
            float4 vv = v[i - nu4];
            x.x += vv.x; x.y += vv.y; x.z += vv.z; x.w += vv.w;
        }
        o[i] = x;
    }
}

// ============================================================
extern "C" void kernel_launch(void* const* d_in, const int* in_sizes, int n_in,
                              void* d_out, int out_size, void* d_ws, size_t ws_size,
                              hipStream_t stream) {
    const float* u_emb = (const float*)d_in[0];
    const float* v_emb = (const float*)d_in[1];
    const int* eu = (const int*)d_in[2];
    const int* ei = (const int*)d_in[3];
    float* out = (float*)d_out;

    const size_t h16bytes = (size_t)N_NODES * D_N * sizeof(ushort_t);  // 32 MB

    size_t off = 0;
    auto carve = [&](size_t bytes) {
        size_t p = off;
        off = (off + bytes + 255) & ~(size_t)255;
        return p;
    };
    char* ws = (char*)d_ws;
    size_t o_dinv  = carve((size_t)N_NODES * 4);
    size_t o_rpu   = carve((size_t)(U_N + 1) * 4);
    size_t o_rpi   = carve((size_t)(I_N + 1) * 4);
    size_t o_bcnt  = carve((size_t)(NB_U + NBMAX) * 4);
    size_t o_bbase = carve((size_t)(NB_U + NBMAX) * 4);
    size_t o_dmat  = carve((size_t)NPB_SORT * 256 * 4);
    size_t o_perm  = carve((size_t)N_NODES * 4);
    size_t o_colu  = carve((size_t)E_N * 4);   // payload only
    size_t o_coli  = carve((size_t)E_N * 4);
    size_t o_ego16 = carve(h16bytes);
    size_t o_h1    = carve(h16bytes);          // aliased: stg_u during build (9.6 MB)
    size_t o_h2    = carve(h16bytes);          // aliased: stg_i during build (9.6 MB)
    size_t needed = off;

    if (ws_size >= needed) {
        float* dinv = (float*)(ws + o_dinv);
        int* rp_u  = (int*)(ws + o_rpu);
        int* rp_i  = (int*)(ws + o_rpi);
        int* bcnt  = (int*)(ws + o_bcnt);
        int* bbase = (int*)(ws + o_bbase);
        int* dmat  = (int*)(ws + o_dmat);
        int* perm  = (int*)(ws + o_perm);
        int* colw_u = (int*)(ws + o_colu);
        int* colw_i = (int*)(ws + o_coli);
        ushort_t* ego16 = (ushort_t*)(ws + o_ego16);
        ushort_t* h1_16 = (ushort_t*)(ws + o_h1);
        ushort_t* h2_16 = (ushort_t*)(ws + o_h2);
        uint* stg_u = (uint*)(ws + o_h1);
        uint* stg_i = (uint*)(ws + o_h2);

        hipMemsetAsync(bcnt, 0, (size_t)(NB_U + NBMAX) * 4, stream);

        cvt16_kernel<<<2048, 256, 0, stream>>>(u_emb, v_emb, ego16);

        const int sblocks = (E_N + CH2 - 1) / CH2;
        stage_both_kernel<<<sblocks, NBMAX, 0, stream>>>(eu, ei, bcnt, stg_u, stg_i);
        bscan_kernel<<<1, NBMAX, 0, stream>>>(bcnt, bbase, rp_u, rp_i);
        csr_finish_kernel<<<NB_U + NB_I, 256, 0, stream>>>(stg_u, stg_i, bcnt, bbase,
                                                           dinv, rp_u, rp_i, colw_u, colw_i);

        // degree-sorted permutation (contention-free 3-phase counting sort)
        deg_hist1_kernel<<<NPB_SORT, 256, 0, stream>>>(rp_u, rp_i, dmat);
        deg_scan2_kernel<<<1, 256, 0, stream>>>(dmat);
        perm_fill3_kernel<<<NPB_SORT, 256, 0, stream>>>(rp_u, rp_i, dmat, perm);

        const int gblocks = ((size_t)N_NODES * 16 + 255) / 256;
        // layer 1: src = ego16 -> h1 bf16
        gather16_kernel<0><<<gblocks, 256, 0, stream>>>(ego16, rp_u, colw_u, rp_i, colw_i,
                                                        dinv, perm, h1_16,
                                                        nullptr, nullptr, nullptr);
        // layer 2: src = h1 -> h2 bf16
        gather16_kernel<0><<<gblocks, 256, 0, stream>>>(h1_16, rp_u, colw_u, rp_i, colw_i,
                                                        dinv, perm, h2_16,
                                                        nullptr, nullptr, nullptr);
        // layer 3: src = h2 -> fused final epilogue (all-bf16 reads) -> out fp32
        gather16_kernel<1><<<gblocks, 256, 0, stream>>>(h2_16, rp_u, colw_u, rp_i, colw_i,
                                                        dinv, perm, nullptr,
                                                        ego16, h1_16, out);
    } else {
        // fallback: R1 atomic-scatter path
        const size_t hbytes = (size_t)N_NODES * D_N * sizeof(float);
        float* dinv = (float*)ws;
        float* bufA = (float*)(ws + (1u << 20));
        float* bufB = bufA + (size_t)N_NODES * D_N;
        hipMemsetAsync(dinv, 0, N_NODES * sizeof(float), stream);
        hipMemsetAsync(bufA, 0, hbytes, stream);
        hipMemsetAsync(bufB, 0, hbytes, stream);
        deg_kernel<<<2048, 256, 0, stream>>>(eu, ei, dinv);
        rsqrt_kernel<<<(N_NODES + 255) / 256, 256, 0, stream>>>(dinv);
        init_out_kernel<<<2048, 256, 0, stream>>>(u_emb, v_emb, out);
        float* bufA_i = bufA + (size_t)U_N * D_N;
        float* bufB_i = bufB + (size_t)U_N * D_N;
        float* out_i  = out + (size_t)U_N * D_N;
        prop_kernel<<<8192, 256, 0, stream>>>(u_emb, v_emb, bufA, bufA_i, eu, ei, dinv);
        add_kernel<<<2048, 256, 0, stream>>>(out, bufA);
        prop_kernel<<<8192, 256, 0, stream>>>(bufA, bufA_i, bufB, bufB_i, eu, ei, dinv);
        add_kernel<<<2048, 256, 0, stream>>>(out, bufB);
        prop_kernel<<<8192, 256, 0, stream>>>(bufB, bufB_i, out, out_i, eu, ei, dinv);
        final_kernel<<<2048, 256, 0, stream>>>(out, v_emb);
    }
}

// Round 14
// 312.482 us; speedup vs baseline: 5.9411x; 1.0812x over previous
//
#include <hip/hip_runtime.h>

#define U_N 150000
#define I_N 100000
#define D_N 64
#define E_N 1500000
#define N_NODES (U_N + I_N)

// bucket geometry
#define BSHIFT 10
#define BW (1 << BSHIFT)              // 1024 keys per bucket
#define NB_U ((U_N + BW - 1) / BW)    // 147
#define NB_I ((I_N + BW - 1) / BW)    // 98
#define NBMAX 256
#define CAP_U 16384
#define CAP_I 24576
#define CH2 4096

typedef unsigned int uint;
typedef unsigned short ushort_t;

// bf16 helpers
__device__ __forceinline__ float bf_lo(uint x) { return __uint_as_float(x << 16); }
__device__ __forceinline__ float bf_hi(uint x) { return __uint_as_float(x & 0xFFFF0000u); }
__device__ __forceinline__ ushort_t f2b(float f) {
    uint u = __float_as_uint(f);
    uint r = u + 0x7FFFu + ((u >> 16) & 1u);   // round-to-nearest-even
    return (ushort_t)(r >> 16);
}
__device__ __forceinline__ void acc4(float4& acc, float wgt, uint2 q) {
    acc.x = fmaf(wgt, bf_lo(q.x), acc.x);
    acc.y = fmaf(wgt, bf_hi(q.x), acc.y);
    acc.z = fmaf(wgt, bf_lo(q.y), acc.z);
    acc.w = fmaf(wgt, bf_hi(q.y), acc.w);
}

// ============================================================
// stage both directions in ONE pass over the edge list.
// staged word = (payload << 10) | (key & 1023)
// ============================================================
__global__ __launch_bounds__(256) void stage_both_kernel(
    const int* __restrict__ eu, const int* __restrict__ ei,
    int* __restrict__ bcnt, uint* __restrict__ stg_u, uint* __restrict__ stg_i) {
    __shared__ uint spu[CH2], spi[CH2];
    __shared__ unsigned char sbu[CH2], sbi[CH2];
    __shared__ int histu[NBMAX], scanu[NBMAX], curu[NBMAX], gbu[NBMAX];
    __shared__ int histi[NBMAX], scani[NBMAX], curi[NBMAX], gbi[NBMAX];
    int tid = threadIdx.x;
    int e0 = blockIdx.x * CH2;
    int cnt = E_N - e0;
    if (cnt <= 0) return;
    if (cnt > CH2) cnt = CH2;

    histu[tid] = 0; histi[tid] = 0;
    __syncthreads();
    for (int s = tid; s < cnt; s += 256) {
        atomicAdd(&histu[eu[e0 + s] >> BSHIFT], 1);
        atomicAdd(&histi[ei[e0 + s] >> BSHIFT], 1);
    }
    __syncthreads();
    scanu[tid] = histu[tid]; scani[tid] = histi[tid];
    __syncthreads();
    for (int off = 1; off < NBMAX; off <<= 1) {
        int vu = (tid >= off) ? scanu[tid - off] : 0;
        int vi = (tid >= off) ? scani[tid - off] : 0;
        __syncthreads();
        scanu[tid] += vu; scani[tid] += vi;
        __syncthreads();
    }
    curu[tid] = scanu[tid] - histu[tid];
    curi[tid] = scani[tid] - histi[tid];
    __syncthreads();
    for (int s = tid; s < cnt; s += 256) {
        int ku = eu[e0 + s], ki = ei[e0 + s];
        int bu = ku >> BSHIFT, bi = ki >> BSHIFT;
        int pu = atomicAdd(&curu[bu], 1);
        spu[pu] = ((uint)ki << BSHIFT) | (uint)(ku & (BW - 1));
        sbu[pu] = (unsigned char)bu;
        int pi = atomicAdd(&curi[bi], 1);
        spi[pi] = ((uint)ku << BSHIFT) | (uint)(ki & (BW - 1));
        sbi[pi] = (unsigned char)bi;
    }
    __syncthreads();
    {
        int cu = histu[tid];
        gbu[tid] = cu ? atomicAdd(&bcnt[tid], cu) : 0;
        int ci = histi[tid];
        gbi[tid] = ci ? atomicAdd(&bcnt[NB_U + tid], ci) : 0;
    }
    __syncthreads();
    for (int s = tid; s < cnt; s += 256) {
        int b = sbu[s];
        int dst = gbu[b] + (s - (scanu[b] - histu[b]));
        if (dst < CAP_U) stg_u[(size_t)b * CAP_U + dst] = spu[s];
    }
    for (int s = tid; s < cnt; s += 256) {
        int b = sbi[s];
        int dst = gbi[b] + (s - (scani[b] - histi[b]));
        if (dst < CAP_I) stg_i[(size_t)b * CAP_I + dst] = spi[s];
    }
}

// ============================================================
// scan bucket totals -> bucket bases; seal rowptr ends
// ============================================================
__global__ void bscan_kernel(const int* __restrict__ bcnt, int* __restrict__ bbase,
                             int* __restrict__ rp_u, int* __restrict__ rp_i) {
    __shared__ int lds[NBMAX];
    int tid = threadIdx.x;
    int v = (tid < NB_U) ? bcnt[tid] : 0;
    lds[tid] = v;
    __syncthreads();
    for (int off = 1; off < NBMAX; off <<= 1) {
        int t = (tid >= off) ? lds[tid - off] : 0;
        __syncthreads();
        lds[tid] += t;
        __syncthreads();
    }
    if (tid < NB_U) bbase[tid] = lds[tid] - v;
    __syncthreads();
    int w = (tid < NB_I) ? bcnt[NB_U + tid] : 0;
    lds[tid] = w;
    __syncthreads();
    for (int off = 1; off < NBMAX; off <<= 1) {
        int t = (tid >= off) ? lds[tid - off] : 0;
        __syncthreads();
        lds[tid] += t;
        __syncthreads();
    }
    if (tid < NB_I) bbase[NB_U + tid] = lds[tid] - w;
    if (tid == 0) { rp_u[U_N] = E_N; rp_i[I_N] = E_N; }
}

// ============================================================
// csr_finish: per-bucket histogram -> dinv + rowptr, then scatter
// ============================================================
__global__ __launch_bounds__(256) void csr_finish_kernel(
    const uint* __restrict__ stg_u, const uint* __restrict__ stg_i,
    const int* __restrict__ bcnt, const int* __restrict__ bbase,
    float* __restrict__ dinv, int* __restrict__ rp_u, int* __restrict__ rp_i,
    int* __restrict__ colw_u, int* __restrict__ colw_i) {
    __shared__ int cnt[BW];
    __shared__ int cur[BW];
    __shared__ int part[256];
    int b = blockIdx.x;
    const uint* stg; int cap, lo, nkeys; float* dside; int* rowptr; int* colw;
    if (b < NB_U) {
        stg = stg_u + (size_t)b * CAP_U; cap = CAP_U; lo = b << BSHIFT;
        nkeys = U_N; dside = dinv; rowptr = rp_u; colw = colw_u;
    } else {
        int bb = b - NB_U;
        stg = stg_i + (size_t)bb * CAP_I; cap = CAP_I; lo = bb << BSHIFT;
        nkeys = I_N; dside = dinv + U_N; rowptr = rp_i; colw = colw_i;
    }
    int ns = bcnt[b]; if (ns > cap) ns = cap;
    int base = bbase[b];
    int hi = lo + BW; if (hi > nkeys) hi = nkeys;
    int nk = hi - lo;
    int tid = threadIdx.x;
    for (int k = tid; k < BW; k += 256) cnt[k] = 0;
    __syncthreads();
    for (int s = tid; s < ns; s += 256)
        atomicAdd(&cnt[stg[s] & (BW - 1)], 1);
    __syncthreads();
    for (int k = tid; k < nk; k += 256)
        dside[lo + k] = rsqrtf((float)cnt[k] + 1e-7f);
    int b4 = tid * 4;
    int v0 = cnt[b4], v1 = cnt[b4 + 1], v2 = cnt[b4 + 2], v3 = cnt[b4 + 3];
    int s = v0 + v1 + v2 + v3;
    part[tid] = s;
    __syncthreads();
    for (int off = 1; off < 256; off <<= 1) {
        int t = (tid >= off) ? part[tid - off] : 0;
        __syncthreads();
        part[tid] += t;
        __syncthreads();
    }
    int run = base + part[tid] - s;
    cur[b4] = run;
    if (b4 < nk) rowptr[lo + b4] = run;
    run += v0;
    cur[b4 + 1] = run;
    if (b4 + 1 < nk) rowptr[lo + b4 + 1] = run;
    run += v1;
    cur[b4 + 2] = run;
    if (b4 + 2 < nk) rowptr[lo + b4 + 2] = run;
    run += v2;
    cur[b4 + 3] = run;
    if (b4 + 3 < nk) rowptr[lo + b4 + 3] = run;
    __syncthreads();
    for (int s2 = tid; s2 < ns; s2 += 256) {
        uint pr = stg[s2];
        int pos = atomicAdd(&cur[pr & (BW - 1)], 1);
        colw[pos] = (int)(pr >> BSHIFT);
    }
}

// ============================================================
// cvt: ego (fp32 u_emb|v_emb) -> bf16 [N][64]
// ============================================================
__global__ void cvt16_kernel(const float* __restrict__ u_emb, const float* __restrict__ v_emb,
                             ushort_t* __restrict__ dst) {
    size_t t = (size_t)blockIdx.x * blockDim.x + threadIdx.x;
    size_t stride = (size_t)gridDim.x * blockDim.x;
    const size_t nu4 = (size_t)U_N * 16;
    const size_t n4 = (size_t)N_NODES * 16;
    const float4* us = (const float4*)u_emb;
    const float4* vs = (const float4*)v_emb;
    ushort4* o = (ushort4*)dst;
    for (size_t i = t; i < n4; i += stride) {
        float4 x = (i < nu4) ? us[i] : vs[i - nu4];
        ushort4 y;
        y.x = f2b(x.x); y.y = f2b(x.y); y.z = f2b(x.z); y.w = f2b(x.w);
        o[i] = y;
    }
}

// ============================================================
// CSR gather: one 16-lane group per node (4 nodes/wave).
// colw = payload only; w = dnbr[nb] (1MB L2-hot broadcast, independent).
// ============================================================
template <int FUSE>
__global__ void gather16_kernel(const ushort_t* __restrict__ src16,
                                const int* __restrict__ rowptr_u, const int* __restrict__ colw_u,
                                const int* __restrict__ rowptr_i, const int* __restrict__ colw_i,
                                const float* __restrict__ dinv,
                                ushort_t* __restrict__ h16_out,
                                const ushort_t* __restrict__ ego16,
                                const ushort_t* __restrict__ h1_16,
                                float* __restrict__ out) {
    int grp = (int)((blockIdx.x * blockDim.x + threadIdx.x) >> 4);
    int d4 = threadIdx.x & 15;
    if (grp >= N_NODES) return;
    const int* rp; const int* cw; const uint2* s8; const float* dnbr; int row;
    if (grp < U_N) {
        rp = rowptr_u; cw = colw_u; row = grp; dnbr = dinv + U_N;
        s8 = (const uint2*)(src16 + (size_t)U_N * D_N);   // items block
    } else {
        rp = rowptr_i; cw = colw_i; row = grp - U_N; dnbr = dinv;
        s8 = (const uint2*)src16;                          // users block
    }
    int beg = rp[row], end = rp[row + 1];

    float4 acc = make_float4(0.f, 0.f, 0.f, 0.f);
    int j = beg;
    while (j + 8 <= end) {
        int c[8]; float wv[8]; uint2 q[8];
#pragma unroll
        for (int t = 0; t < 8; ++t) c[t] = cw[j + t];
#pragma unroll
        for (int t = 0; t < 8; ++t) wv[t] = dnbr[c[t]];
#pragma unroll
        for (int t = 0; t < 8; ++t) q[t] = s8[(size_t)c[t] * 16 + d4];
#pragma unroll
        for (int t = 0; t < 8; ++t) acc4(acc, wv[t], q[t]);
        j += 8;
    }
    if (j + 4 <= end) {
        int c[4]; float wv[4]; uint2 q[4];
#pragma unroll
        for (int t = 0; t < 4; ++t) c[t] = cw[j + t];
#pragma unroll
        for (int t = 0; t < 4; ++t) wv[t] = dnbr[c[t]];
#pragma unroll
        for (int t = 0; t < 4; ++t) q[t] = s8[(size_t)c[t] * 16 + d4];
#pragma unroll
        for (int t = 0; t < 4; ++t) acc4(acc, wv[t], q[t]);
        j += 4;
    }
    for (; j < end; ++j) {
        int c = cw[j];
        float wgt = dnbr[c];
        uint2 q = s8[(size_t)c * 16 + d4];
        acc4(acc, wgt, q);
    }

    float sc = rsqrtf((float)(end - beg) + 1e-7f);
    acc.x *= sc; acc.y *= sc; acc.z *= sc; acc.w *= sc;

    if (FUSE == 0) {
        ushort4 o;
        o.x = f2b(acc.x); o.y = f2b(acc.y); o.z = f2b(acc.z); o.w = f2b(acc.w);
        ((ushort4*)h16_out)[(size_t)grp * 16 + d4] = o;
    } else {
        // out = 0.25*(ego + h1 + h2 + h3) (+ ego again for items); bf16 ego/h1/h2
        uint2 e  = ((const uint2*)ego16)[(size_t)grp * 16 + d4];
        uint2 p1 = ((const uint2*)h1_16)[(size_t)grp * 16 + d4];
        uint2 p2 = ((const uint2*)src16)[(size_t)grp * 16 + d4];  // src16 == h2
        float ex = bf_lo(e.x), ey = bf_hi(e.x), ez = bf_lo(e.y), ew = bf_hi(e.y);
        float4 r;
        r.x = 0.25f * (ex + bf_lo(p1.x) + bf_lo(p2.x) + acc.x);
        r.y = 0.25f * (ey + bf_hi(p1.x) + bf_hi(p2.x) + acc.y);
        r.z = 0.25f * (ez + bf_lo(p1.y) + bf_lo(p2.y) + acc.z);
        r.w = 0.25f * (ew + bf_hi(p1.y) + bf_hi(p2.y) + acc.w);
        if (grp >= U_N) { r.x += ex; r.y += ey; r.z += ez; r.w += ew; }
        ((float4*)out)[(size_t)grp * 16 + d4] = r;
    }
}

// ============================================================
// fallback (R1 atomic path) kernels, used only if ws too small
// ============================================================
__global__ void deg_kernel(const int* __restrict__ eu, const int* __restrict__ ei,
                           float* __restrict__ deg) {
    int t = blockIdx.x * blockDim.x + threadIdx.x;
    int stride = gridDim.x * blockDim.x;
    for (int e = t; e < E_N; e += stride) {
        atomicAdd(&deg[eu[e]], 1.0f);
        atomicAdd(&deg[U_N + ei[e]], 1.0f);
    }
}
__global__ void rsqrt_kernel(float* __restrict__ deg) {
    int t = blockIdx.x * blockDim.x + threadIdx.x;
    if (t < N_NODES) deg[t] = rsqrtf(deg[t] + 1e-7f);
}
__global__ void init_out_kernel(const float* __restrict__ u_emb,
                                const float* __restrict__ v_emb,
                                float* __restrict__ out) {
    size_t t = (size_t)blockIdx.x * blockDim.x + threadIdx.x;
    size_t stride = (size_t)gridDim.x * blockDim.x;
    const size_t nu4 = (size_t)U_N * D_N / 4;
    const size_t ni4 = (size_t)I_N * D_N / 4;
    const float4* us = (const float4*)u_emb;
    const float4* vs = (const float4*)v_emb;
    float4* o = (float4*)out;
    for (size_t i = t; i < nu4; i += stride) o[i] = us[i];
    for (size_t i = t; i < ni4; i += stride) o[nu4 + i] = vs[i];
}
__global__ void add_kernel(float* __restrict__ acc, const float* __restrict__ h) {
    size_t t = (size_t)blockIdx.x * blockDim.x + threadIdx.x;
    size_t stride = (size_t)gridDim.x * blockDim.x;
    const size_t n4 = (size_t)N_NODES * D_N / 4;
    float4* a = (float4*)acc;
    const float4* b = (const float4*)h;
    for (size_t i = t; i < n4; i += stride) {
        float4 x = a[i]; float4 y = b[i];
        x.x += y.x; x.y += y.y; x.z += y.z; x.w += y.w;
        a[i] = x;
    }
}
__global__ void prop_kernel(const float* __restrict__ srcU, const float* __restrict__ srcI,
                            float* __restrict__ dstU, float* __restrict__ dstI,
                            const int* __restrict__ eu, const int* __restrict__ ei,
                            const float* __restrict__ dinv) {
    int wave = (blockIdx.x * blockDim.x + threadIdx.x) >> 6;
    int lane = threadIdx.x & 63;
    int nwaves = (gridDim.x * blockDim.x) >> 6;
    for (int e = wave; e < E_N; e += nwaves) {
        int u = eu[e];
        int i = ei[e];
        float w = dinv[u] * dinv[U_N + i];
        float hu = srcU[(size_t)u * D_N + lane];
        float hi = srcI[(size_t)i * D_N + lane];
        atomicAdd(&dstU[(size_t)u * D_N + lane], w * hi);
        atomicAdd(&dstI[(size_t)i * D_N + lane], w * hu);
    }
}
__global__ void final_kernel(float* __restrict__ out, const float* __restrict__ v_emb) {
    size_t t = (size_t)blockIdx.x * blockDim.x + threadIdx.x;
    size_t stride = (size_t)gridDim.x * blockDim.x;
    const size_t nu4 = (size_t)U_N * D_N / 4;
    const size_t n4 = (size_t)N_NODES * D_N / 4;
    float4* o = (float4*)out;
    const float4* v = (const float4*)v_emb;
    for (size_t i = t; i < n4; i += stride) {
        float4 x = o[i];
        x.x *= 0.25f; x.y *= 0.25f; x.z *= 0.25f; x.w *= 0.25f;
        if (i >= nu4) {
            float4 vv = v[i - nu4];
            x.x += vv.x; x.y += vv.y; x.z += vv.z; x.w += vv.w;
        }
        o[i] = x;
    }
}

// ============================================================
extern "C" void kernel_launch(void* const* d_in, const int* in_sizes, int n_in,
                              void* d_out, int out_size, void* d_ws, size_t ws_size,
                              hipStream_t stream) {
    const float* u_emb = (const float*)d_in[0];
    const float* v_emb = (const float*)d_in[1];
    const int* eu = (const int*)d_in[2];
    const int* ei = (const int*)d_in[3];
    float* out = (float*)d_out;

    const size_t h16bytes = (size_t)N_NODES * D_N * sizeof(ushort_t);  // 32 MB

    size_t off = 0;
    auto carve = [&](size_t bytes) {
        size_t p = off;
        off = (off + bytes + 255) & ~(size_t)255;
        return p;
    };
    char* ws = (char*)d_ws;
    size_t o_dinv  = carve((size_t)N_NODES * 4);
    size_t o_rpu   = carve((size_t)(U_N + 1) * 4);
    size_t o_rpi   = carve((size_t)(I_N + 1) * 4);
    size_t o_bcnt  = carve((size_t)(NB_U + NBMAX) * 4);
    size_t o_bbase = carve((size_t)(NB_U + NBMAX) * 4);
    size_t o_colu  = carve((size_t)E_N * 4);   // payload only
    size_t o_coli  = carve((size_t)E_N * 4);
    size_t o_ego16 = carve(h16bytes);
    size_t o_h1    = carve(h16bytes);          // aliased: stg_u during build (9.6 MB)
    size_t o_h2    = carve(h16bytes);          // aliased: stg_i during build (9.6 MB)
    size_t needed = off;

    if (ws_size >= needed) {
        float* dinv = (float*)(ws + o_dinv);
        int* rp_u  = (int*)(ws + o_rpu);
        int* rp_i  = (int*)(ws + o_rpi);
        int* bcnt  = (int*)(ws + o_bcnt);
        int* bbase = (int*)(ws + o_bbase);
        int* colw_u = (int*)(ws + o_colu);
        int* colw_i = (int*)(ws + o_coli);
        ushort_t* ego16 = (ushort_t*)(ws + o_ego16);
        ushort_t* h1_16 = (ushort_t*)(ws + o_h1);
        ushort_t* h2_16 = (ushort_t*)(ws + o_h2);
        uint* stg_u = (uint*)(ws + o_h1);
        uint* stg_i = (uint*)(ws + o_h2);

        hipMemsetAsync(bcnt, 0, (size_t)(NB_U + NBMAX) * 4, stream);

        cvt16_kernel<<<2048, 256, 0, stream>>>(u_emb, v_emb, ego16);

        const int sblocks = (E_N + CH2 - 1) / CH2;
        stage_both_kernel<<<sblocks, NBMAX, 0, stream>>>(eu, ei, bcnt, stg_u, stg_i);
        bscan_kernel<<<1, NBMAX, 0, stream>>>(bcnt, bbase, rp_u, rp_i);
        csr_finish_kernel<<<NB_U + NB_I, 256, 0, stream>>>(stg_u, stg_i, bcnt, bbase,
                                                           dinv, rp_u, rp_i, colw_u, colw_i);

        const int gblocks = ((size_t)N_NODES * 16 + 255) / 256;
        // layer 1: src = ego16 -> h1 bf16 (stg_u dead after csr_finish)
        gather16_kernel<0><<<gblocks, 256, 0, stream>>>(ego16, rp_u, colw_u, rp_i, colw_i,
                                                        dinv, h1_16, nullptr, nullptr, nullptr);
        // layer 2: src = h1 -> h2 bf16 (stg_i dead after csr_finish)
        gather16_kernel<0><<<gblocks, 256, 0, stream>>>(h1_16, rp_u, colw_u, rp_i, colw_i,
                                                        dinv, h2_16, nullptr, nullptr, nullptr);
        // layer 3: src = h2 -> fused final epilogue (all-bf16 reads) -> out fp32
        gather16_kernel<1><<<gblocks, 256, 0, stream>>>(h2_16, rp_u, colw_u, rp_i, colw_i,
                                                        dinv, nullptr, ego16, h1_16, out);
    } else {
        // fallback: R1 atomic-scatter path
        const size_t hbytes = (size_t)N_NODES * D_N * sizeof(float);
        float* dinv = (float*)ws;
        float* bufA = (float*)(ws + (1u << 20));
        float* bufB = bufA + (size_t)N_NODES * D_N;
        hipMemsetAsync(dinv, 0, N_NODES * sizeof(float), stream);
        hipMemsetAsync(bufA, 0, hbytes, stream);
        hipMemsetAsync(bufB, 0, hbytes, stream);
        deg_kernel<<<2048, 256, 0, stream>>>(eu, ei, dinv);
        rsqrt_kernel<<<(N_NODES + 255) / 256, 256, 0, stream>>>(dinv);
        init_out_kernel<<<2048, 256, 0, stream>>>(u_emb, v_emb, out);
        float* bufA_i = bufA + (size_t)U_N * D_N;
        float* bufB_i = bufB + (size_t)U_N * D_N;
        float* out_i  = out + (size_t)U_N * D_N;
        prop_kernel<<<8192, 256, 0, stream>>>(u_emb, v_emb, bufA, bufA_i, eu, ei, dinv);
        add_kernel<<<2048, 256, 0, stream>>>(out, bufA);
        prop_kernel<<<8192, 256, 0, stream>>>(bufA, bufA_i, bufB, bufB_i, eu, ei, dinv);
        add_kernel<<<2048, 256, 0, stream>>>(out, bufB);
        prop_kernel<<<8192, 256, 0, stream>>>(bufB, bufB_i, out, out_i, eu, ei, dinv);
        final_kernel<<<2048, 256, 0, stream>>>(out, v_emb);
    }
}